// Round 12
// baseline (794.736 us; speedup 1.0000x reference)
//
#include <hip/hip_runtime.h>
#include <math.h>

typedef __attribute__((ext_vector_type(8))) short short8;
typedef __attribute__((ext_vector_type(4))) float f32x4;

#define NCB 4
#define NE 1024
#define DIM 64
#define HW 16384
#define NPIX 131072
#define NWAVES 4096            // 1024 blocks * 4 waves
#define MSE_DENOM 8388608.0f   // NPIX*DIM
#define EPSF 1e-5f
#define SPLIT_BYTES 131072     // 1024 codes * 128B
#define CB_BYTES    393216     // 3 splits * SPLIT_BYTES

__device__ __forceinline__ unsigned short f2bf(float x) {  // RNE fp32->bf16
    unsigned u = __float_as_uint(x);
    u += 0x7fffu + ((u >> 16) & 1u);
    return (unsigned short)(u >> 16);
}
__device__ __forceinline__ float bf2f(unsigned short h) {  // exact bf16->fp32
    return __uint_as_float(((unsigned)h) << 16);
}

// ------------- kernel 0: -0.5*||e||^2 per code (fp32, exact) -------------
__global__ __launch_bounds__(64) void rvq_norms(const float* __restrict__ cb,
                                                float* __restrict__ nrmh) {
    int code = blockIdx.x * 64 + threadIdx.x;  // 0..4095
    const float4* row = reinterpret_cast<const float4*>(cb + (size_t)code * DIM);
    float s0 = 0.f, s1 = 0.f, s2 = 0.f, s3 = 0.f;
#pragma unroll
    for (int k = 0; k < 16; ++k) {
        float4 v = row[k];
        s0 = fmaf(v.x, v.x, s0); s1 = fmaf(v.y, v.y, s1);
        s2 = fmaf(v.z, v.z, s2); s3 = fmaf(v.w, v.w, s3);
    }
    nrmh[code] = -0.5f * ((s0 + s1) + (s2 + s3));
}

// ------------- kernel 0b: pre-split codebook -> LINEAR bf16x3 image ------
// Layout: [cb i][split s][code][dim] bf16 — no swizzle (no LDS anymore;
// the wave's 64 lanes read disjoint 16B of a contiguous 1KB span -> fully
// coalesced L2 streams).
__global__ __launch_bounds__(256) void rvq_presplit(const float* __restrict__ cb,
                                                    unsigned short* __restrict__ gB) {
    int blk = blockIdx.x;            // i*16 + c64
    int tid = threadIdx.x;
    int code64 = tid >> 2, dg = tid & 3;
    int c0 = (blk & 15) << 6;
    int i  = blk >> 4;
    int C  = c0 + code64;            // global code within codebook
    const float4* s4 = reinterpret_cast<const float4*>(
        cb + ((size_t)i * NE + C) * DIM + dg * 16);
    float v[16];
    {
        float4 q;
        q = s4[0]; v[0]=q.x; v[1]=q.y; v[2]=q.z; v[3]=q.w;
        q = s4[1]; v[4]=q.x; v[5]=q.y; v[6]=q.z; v[7]=q.w;
        q = s4[2]; v[8]=q.x; v[9]=q.y; v[10]=q.z; v[11]=q.w;
        q = s4[3]; v[12]=q.x; v[13]=q.y; v[14]=q.z; v[15]=q.w;
    }
    char* gBi = reinterpret_cast<char*>(gB) + (size_t)i * CB_BYTES;
#pragma unroll
    for (int h = 0; h < 2; ++h) {
        short8 p1, p2, p3;
#pragma unroll
        for (int e = 0; e < 8; ++e) {
            float t = v[h * 8 + e];
            unsigned short u1 = f2bf(t); t -= bf2f(u1);
            unsigned short u2 = f2bf(t); t -= bf2f(u2);
            unsigned short u3 = f2bf(t);
            p1[e] = (short)u1; p2[e] = (short)u2; p3[e] = (short)u3;
        }
        int a = C * 128 + dg * 32 + h * 16;   // bytes within a split plane
        *reinterpret_cast<short8*>(gBi + a)                  = p1;
        *reinterpret_cast<short8*>(gBi + SPLIT_BYTES + a)    = p2;
        *reinterpret_cast<short8*>(gBi + 2 * SPLIT_BYTES + a)= p3;
    }
}

// ------------- kernel 1: MFMA RVQ, barrier-free L2-streaming scan --------
// 1024 blocks x 4 waves; wave owns 32 pixels (two 16-row A-tiles), fully
// independent (NO __syncthreads in the kernel). B fragments stream from
// the L2-resident 1.5MB pre-split image straight into registers, consumed
// immediately by MFMA (no staging lifetime -> no spill exposure; the
// R7/R10/R11 lesson: only the 256-reg bracket is spill-free, so take
// (256,2) and win back the stall time by removing all barrier drains and
// the LDS round-trip — the image L2-fits, Common-mistake #7).
// Depth-1 software pipeline, even/odd named B buffers (static indexing).
// State = bf16x3 A-frags (R10/R11-validated rebuild epilogue).
// s = r.e - 0.5||e||^2 in-MFMA; argmax s == argmin dist; ascending-code
// strict-> scan + idx tie-break = jnp.argmin first-min semantics.
__global__ __launch_bounds__(256, 2) void rvq_main(
    const float* __restrict__ z, const unsigned short* __restrict__ gB,
    const float* __restrict__ nrmh, const float* __restrict__ cb,
    float* __restrict__ out_zq, float* __restrict__ out_idx,
    unsigned* __restrict__ hist, float* __restrict__ msePartial)
{
    __shared__ int sBest[4][32];   // wave-private (wid-indexed): no barrier

    const int tid  = threadIdx.x;
    const int lane = tid & 63;
    const int wid  = tid >> 6;
    const int col  = lane & 15;   // A-row within tile / D-col (code)
    const int g    = lane >> 4;   // k-group (8 dims) / D row-group
    const int blockPix = blockIdx.x * 128;
    const int lo = g * 16;        // per-lane byte offset within a code row

    // persistent state: bf16x3 A-frags [split][m][kh]
    short8 A[3][2][2];
#pragma unroll
    for (int m = 0; m < 2; ++m) {
        int pf = blockPix + wid * 32 + m * 16 + col;
        size_t zb = (size_t)(pf >> 14) * 1048576 + (size_t)(pf & 16383);
#pragma unroll
        for (int kh = 0; kh < 2; ++kh)
#pragma unroll
            for (int e = 0; e < 8; ++e) {
                float t = z[zb + (size_t)(kh * 32 + g * 8 + e) * HW];
                unsigned short u1 = f2bf(t); t -= bf2f(u1);
                unsigned short u2 = f2bf(t); t -= bf2f(u2);
                unsigned short u3 = f2bf(t);
                A[0][m][kh][e] = (short)u1;
                A[1][m][kh][e] = (short)u2;
                A[2][m][kh][e] = (short)u3;
            }
    }

    for (int i = 0; i < NCB; ++i) {
        const char* gBi = reinterpret_cast<const char*>(gB) + (size_t)i * CB_BYTES;
        const float* nrm_i = nrmh + i * NE;

        float maxv[2][4]; int maxi[2][4];
#pragma unroll
        for (int m = 0; m < 2; ++m)
#pragma unroll
            for (int rr = 0; rr < 4; ++rr) { maxv[m][rr] = -3.4e38f; maxi[m][rr] = 0; }

        short8 Ba[3][2], Bb[3][2];
        {   // preload sub=0 (codes col..col+? : code = col)
            int a = (col << 7) + lo;
#pragma unroll
            for (int sb = 0; sb < 3; ++sb) {
                Ba[sb][0] = *reinterpret_cast<const short8*>(gBi + sb * SPLIT_BYTES + a);
                Ba[sb][1] = *reinterpret_cast<const short8*>(gBi + sb * SPLIT_BYTES + a + 64);
            }
        }

#define SUB_BODY(SUB, BCUR, BNXT, DO_PREFETCH)                                         \
        {                                                                              \
            const int code = ((SUB) << 4) + col;                                       \
            if (DO_PREFETCH) {                                                         \
                int a = ((code + 16) << 7) + lo;                                       \
                _Pragma("unroll")                                                      \
                for (int sb = 0; sb < 3; ++sb) {                                       \
                    BNXT[sb][0] = *reinterpret_cast<const short8*>(gBi + sb * SPLIT_BYTES + a);        \
                    BNXT[sb][1] = *reinterpret_cast<const short8*>(gBi + sb * SPLIT_BYTES + a + 64);   \
                }                                                                      \
            }                                                                          \
            float nh = nrm_i[code];                                                    \
            f32x4 acc[2];                                                              \
            _Pragma("unroll")                                                          \
            for (int rr = 0; rr < 4; ++rr) { acc[0][rr] = nh; acc[1][rr] = nh; }       \
            __builtin_amdgcn_s_setprio(1);                                             \
            _Pragma("unroll")                                                          \
            for (int sb = 0; sb < 3; ++sb) {                                           \
                _Pragma("unroll")                                                      \
                for (int sa = 0; sa < 3 - sb; ++sa) {                                  \
                    acc[0] = __builtin_amdgcn_mfma_f32_16x16x32_bf16(A[sa][0][0], BCUR[sb][0], acc[0], 0, 0, 0); \
                    acc[1] = __builtin_amdgcn_mfma_f32_16x16x32_bf16(A[sa][1][0], BCUR[sb][0], acc[1], 0, 0, 0); \
                    acc[0] = __builtin_amdgcn_mfma_f32_16x16x32_bf16(A[sa][0][1], BCUR[sb][1], acc[0], 0, 0, 0); \
                    acc[1] = __builtin_amdgcn_mfma_f32_16x16x32_bf16(A[sa][1][1], BCUR[sb][1], acc[1], 0, 0, 0); \
                }                                                                      \
            }                                                                          \
            __builtin_amdgcn_s_setprio(0);                                             \
            _Pragma("unroll")                                                          \
            for (int m = 0; m < 2; ++m)                                                \
                _Pragma("unroll")                                                      \
                for (int rr = 0; rr < 4; ++rr) {                                       \
                    float s = acc[m][rr];                                              \
                    if (s > maxv[m][rr]) { maxv[m][rr] = s; maxi[m][rr] = code; }      \
                }                                                                      \
        }

        for (int sp = 0; sp < 32; ++sp) {
            SUB_BODY(2 * sp,     Ba, Bb, 1)            // prefetch sub 2sp+1 (<=63)
            SUB_BODY(2 * sp + 1, Bb, Ba, (sp < 31))    // prefetch sub 2sp+2 (guarded)
        }
#undef SUB_BODY

        // cross-lane argmax within each 16-lane group, idx tie-break
#pragma unroll
        for (int m = 0; m < 2; ++m)
#pragma unroll
            for (int rr = 0; rr < 4; ++rr) {
                float v = maxv[m][rr]; int ix = maxi[m][rr];
#pragma unroll
                for (int off = 1; off < 16; off <<= 1) {
                    float ov = __shfl_xor(v, off, 64);
                    int   oi = __shfl_xor(ix, off, 64);
                    if (ov > v || (ov == v && oi < ix)) { v = ov; ix = oi; }
                }
                maxi[m][rr] = ix;
            }
        // wave-private exchange via LDS (same-wave ds ordering, no barrier)
        if (col == 0) {
#pragma unroll
            for (int m = 0; m < 2; ++m)
#pragma unroll
                for (int rr = 0; rr < 4; ++rr)
                    sBest[wid][m * 16 + g * 4 + rr] = maxi[m][rr];
        }

        const float* cbi = cb + (size_t)i * NE * DIM;
        if (lane < 16) {  // idx output + histogram, one writer per row
#pragma unroll
            for (int m = 0; m < 2; ++m) {
                int pfr = blockPix + wid * 32 + m * 16 + lane;
                int bb = pfr >> 14, yy = (pfr >> 7) & 127, xx = pfr & 127;
                int bi = sBest[wid][m * 16 + lane];
                size_t off = (size_t)bb * 65536 + (size_t)(yy >> 2) * 2048
                           + (size_t)(xx >> 2) * 64
                           + (size_t)(((yy & 3) << 2) + (xx & 3)) * 4 + (size_t)i;
                out_idx[off] = (float)bi;
                atomicAdd(&hist[i * NE + bi], 1u);
            }
        }

        // ---- scoped epilogue: rebuild r from A, update, re-split ----
        {
            float msum = 0.f;
#pragma unroll
            for (int m = 0; m < 2; ++m) {
                const int best = sBest[wid][m * 16 + col];
                const float* er = cbi + (size_t)best * DIM + g * 8;
#pragma unroll
                for (int kh = 0; kh < 2; ++kh) {
                    float4 q0 = *reinterpret_cast<const float4*>(er + kh * 32);
                    float4 q1 = *reinterpret_cast<const float4*>(er + kh * 32 + 4);
                    float te[8];
                    te[0] = (bf2f((unsigned short)A[0][m][kh][0]) + bf2f((unsigned short)A[1][m][kh][0]) + bf2f((unsigned short)A[2][m][kh][0])) - q0.x;
                    te[1] = (bf2f((unsigned short)A[0][m][kh][1]) + bf2f((unsigned short)A[1][m][kh][1]) + bf2f((unsigned short)A[2][m][kh][1])) - q0.y;
                    te[2] = (bf2f((unsigned short)A[0][m][kh][2]) + bf2f((unsigned short)A[1][m][kh][2]) + bf2f((unsigned short)A[2][m][kh][2])) - q0.z;
                    te[3] = (bf2f((unsigned short)A[0][m][kh][3]) + bf2f((unsigned short)A[1][m][kh][3]) + bf2f((unsigned short)A[2][m][kh][3])) - q0.w;
                    te[4] = (bf2f((unsigned short)A[0][m][kh][4]) + bf2f((unsigned short)A[1][m][kh][4]) + bf2f((unsigned short)A[2][m][kh][4])) - q1.x;
                    te[5] = (bf2f((unsigned short)A[0][m][kh][5]) + bf2f((unsigned short)A[1][m][kh][5]) + bf2f((unsigned short)A[2][m][kh][5])) - q1.y;
                    te[6] = (bf2f((unsigned short)A[0][m][kh][6]) + bf2f((unsigned short)A[1][m][kh][6]) + bf2f((unsigned short)A[2][m][kh][6])) - q1.z;
                    te[7] = (bf2f((unsigned short)A[0][m][kh][7]) + bf2f((unsigned short)A[1][m][kh][7]) + bf2f((unsigned short)A[2][m][kh][7])) - q1.w;
#pragma unroll
                    for (int e = 0; e < 8; ++e) msum = fmaf(te[e], te[e], msum);
                    if (i < NCB - 1) {   // re-split r_new -> A (state for next cb)
                        short8 n0, n1, n2;
#pragma unroll
                        for (int e = 0; e < 8; ++e) {
                            float t = te[e];
                            unsigned short u1 = f2bf(t); t -= bf2f(u1);
                            unsigned short u2 = f2bf(t); t -= bf2f(u2);
                            n0[e] = (short)u1; n1[e] = (short)u2; n2[e] = (short)f2bf(t);
                        }
                        A[0][m][kh] = n0; A[1][m][kh] = n1; A[2][m][kh] = n2;
                    } else {             // final: z_q = z - r_final (telescoped)
                        int pf = blockPix + wid * 32 + m * 16 + col;
                        size_t zb = (size_t)(pf >> 14) * 1048576 + (size_t)(pf & 16383);
#pragma unroll
                        for (int e = 0; e < 8; ++e) {
                            size_t o = zb + (size_t)(kh * 32 + g * 8 + e) * HW;
                            out_zq[o] = z[o] - te[e];
                        }
                    }
                }
            }
            // MSE partial: (z_q - r_old)^2 = r_new^2
#pragma unroll
            for (int d_ = 32; d_ > 0; d_ >>= 1) msum += __shfl_down(msum, d_, 64);
            if (lane == 0) msePartial[i * NWAVES + blockIdx.x * 4 + wid] = msum;
        }
    }
}

// ---------------- kernel 2: deterministic loss finalize ----------------
__global__ __launch_bounds__(1024) void rvq_finalize(
    const unsigned* __restrict__ hist, const float* __restrict__ msePartial,
    float* __restrict__ out_loss)
{
    __shared__ float red[1024];
    int t = threadIdx.x;
    float loss = 0.f;
    for (int i = 0; i < NCB; ++i) {
        float cnt = (float)hist[i * NE + t];
        float prob = (cnt + EPSF) / (131072.0f + EPSF * 1024.0f);
        red[t] = -prob * logf(prob + EPSF);
        __syncthreads();
        for (int s = 512; s > 0; s >>= 1) { if (t < s) red[t] += red[t + s]; __syncthreads(); }
        float entropy = red[0];
        __syncthreads();
        float acc = 0.f;
#pragma unroll
        for (int k = 0; k < 4; ++k) acc += msePartial[i * NWAVES + k * 1024 + t];
        red[t] = acc;
        __syncthreads();
        for (int s = 512; s > 0; s >>= 1) { if (t < s) red[t] += red[t + s]; __syncthreads(); }
        float mse_sum = red[0];
        __syncthreads();
        loss += 0.25f * (mse_sum / MSE_DENOM) + 0.01f * (logf(1024.0f) - entropy);
    }
    if (t == 0) out_loss[0] = loss;
}

extern "C" void kernel_launch(void* const* d_in, const int* in_sizes, int n_in,
                              void* d_out, int out_size, void* d_ws, size_t ws_size,
                              hipStream_t stream) {
    const float* z  = (const float*)d_in[0];
    const float* cb = (const float*)d_in[1];

    float* out      = (float*)d_out;
    float* out_zq   = out;                    // 8388608
    float* out_loss = out + 8388608;          // 1
    float* out_idx  = out + 8388609;          // 524288 (indices as float)

    unsigned* hist        = (unsigned*)d_ws;                         // 16 KB
    float*    nrmh        = (float*)((char*)d_ws + 16384);           // 16 KB
    float*    msePartial  = (float*)((char*)d_ws + 32768);           // 64 KB (4*4096 f32)
    unsigned short* gB    = (unsigned short*)((char*)d_ws + 163840); // 1.5 MB pre-split image

    hipMemsetAsync(d_ws, 0, 16384, stream);   // zero histogram (deterministic)
    rvq_norms<<<64, 64, 0, stream>>>(cb, nrmh);
    rvq_presplit<<<64, 256, 0, stream>>>(cb, gB);
    rvq_main<<<1024, 256, 0, stream>>>(z, gB, nrmh, cb, out_zq, out_idx, hist, msePartial);
    rvq_finalize<<<1, 1024, 0, stream>>>(hist, msePartial, out_loss);
}

// Round 13
// 384.621 us; speedup vs baseline: 2.0663x; 2.0663x over previous
//
#include <hip/hip_runtime.h>
#include <math.h>

typedef __attribute__((ext_vector_type(8))) short short8;
typedef __attribute__((ext_vector_type(4))) float f32x4;

#define NCB 4
#define NE 1024
#define DIM 64
#define HW 16384
#define NPIX 131072
#define NWAVES 4096            // 1024 blocks * 4 waves
#define MSE_DENOM 8388608.0f   // NPIX*DIM
#define EPSF 1e-5f
#define CHUNK_BYTES 24576      // 3 splits * 64 codes * 64 dims * 2B
#define CHUNK_SHORTS 12288
#define NCHUNK 16              // chunks per codebook

__device__ __forceinline__ unsigned short f2bf(float x) {  // RNE fp32->bf16
    unsigned u = __float_as_uint(x);
    u += 0x7fffu + ((u >> 16) & 1u);
    return (unsigned short)(u >> 16);
}
__device__ __forceinline__ float bf2f(unsigned short h) {  // exact bf16->fp32
    return __uint_as_float(((unsigned)h) << 16);
}

// ------------- kernel 0: -0.5*||e||^2 per code (fp32, exact) -------------
__global__ __launch_bounds__(64) void rvq_norms(const float* __restrict__ cb,
                                                float* __restrict__ nrmh) {
    int code = blockIdx.x * 64 + threadIdx.x;  // 0..4095
    const float4* row = reinterpret_cast<const float4*>(cb + (size_t)code * DIM);
    float s0 = 0.f, s1 = 0.f, s2 = 0.f, s3 = 0.f;
#pragma unroll
    for (int k = 0; k < 16; ++k) {
        float4 v = row[k];
        s0 = fmaf(v.x, v.x, s0); s1 = fmaf(v.y, v.y, s1);
        s2 = fmaf(v.z, v.z, s2); s3 = fmaf(v.w, v.w, s3);
    }
    nrmh[code] = -0.5f * ((s0 + s1) + (s2 + s3));
}

// ------------- kernel 0b: pre-split codebook -> swizzled bf16x3 image ----
// R5-validated layout: [cb i][chunk c(64 codes)] 24KB blobs, 3 planes of
// 8192B, addr=(code*128+dg*32+h*16)^((code&7)<<4). Byte-identical to the
// main kernel's LDS chunk buffer.
__global__ __launch_bounds__(256) void rvq_presplit(const float* __restrict__ cb,
                                                    unsigned short* __restrict__ gB) {
    int blk = blockIdx.x;            // i*16 + c
    int tid = threadIdx.x;
    int code = tid >> 2, dg = tid & 3;
    int c0 = (blk & 15) << 6;
    int i  = blk >> 4;
    const float4* s4 = reinterpret_cast<const float4*>(
        cb + ((size_t)i * NE + c0 + code) * DIM + dg * 16);
    float v[16];
    {
        float4 q;
        q = s4[0]; v[0]=q.x; v[1]=q.y; v[2]=q.z; v[3]=q.w;
        q = s4[1]; v[4]=q.x; v[5]=q.y; v[6]=q.z; v[7]=q.w;
        q = s4[2]; v[8]=q.x; v[9]=q.y; v[10]=q.z; v[11]=q.w;
        q = s4[3]; v[12]=q.x; v[13]=q.y; v[14]=q.z; v[15]=q.w;
    }
    char* outc = reinterpret_cast<char*>(gB + (size_t)blk * CHUNK_SHORTS);
    int linbase = code * 128 + dg * 32;
    int sw = (code & 7) << 4;
#pragma unroll
    for (int h = 0; h < 2; ++h) {
        short8 p1, p2, p3;
#pragma unroll
        for (int e = 0; e < 8; ++e) {
            float t = v[h * 8 + e];
            unsigned short u1 = f2bf(t); t -= bf2f(u1);
            unsigned short u2 = f2bf(t); t -= bf2f(u2);
            unsigned short u3 = f2bf(t);
            p1[e] = (short)u1; p2[e] = (short)u2; p3[e] = (short)u3;
        }
        int a = (linbase + h * 16) ^ sw;
        *reinterpret_cast<short8*>(outc + a)         = p1;
        *reinterpret_cast<short8*>(outc + 8192 + a)  = p2;
        *reinterpret_cast<short8*>(outc + 16384 + a) = p3;
    }
}

// async 16B/lane global->LDS: wave-uniform LDS base, per-lane global src.
__device__ __forceinline__ void gload16(const void* gsrc, void* ldst) {
    __builtin_amdgcn_global_load_lds(
        (const __attribute__((address_space(1))) unsigned int*)gsrc,
        (__attribute__((address_space(3))) unsigned int*)ldst, 16, 0, 0);
}

// ------------- kernel 1: MFMA RVQ, M=32, T3/T4 counted-vmcnt pipeline ----
// 1024 blocks x 4 waves, (256,2) — the only spill-free bracket for the
// M=32 scan (R7/R10/R11 falsified tighter caps). The R6 anchor (402us,
// MfmaUtil 43) paid ~180us in per-chunk __syncthreads full drains
// (vmcnt(0)): at 2 waves/SIMD nothing hides the drain. This version keeps
// the next chunk's 6 global_load_lds IN FLIGHT across a raw s_barrier:
//   iter c: [issue 6 gloads(c+1) -> buf[(c+1)%3]; s_waitcnt vmcnt(6)
//            (own gloads(c) done); s_barrier (all waves' gloads(c) done);
//            compute chunk c from buf[c%3]]
// Triple buffer: gload(c+1) writes the buffer last READ at iter c-2;
// barrier at iter c-1 separates (wave issues only after passing it).
// One __syncthreads per codebook boundary guards cross-cb reuse.
// Numerics identical to R6 lineage (chained acc validated R7).
__global__ __launch_bounds__(256, 2) void rvq_main(
    const float* __restrict__ z, const unsigned short* __restrict__ gB,
    const float* __restrict__ nrmh, const float* __restrict__ cb,
    float* __restrict__ out_zq, float* __restrict__ out_idx,
    unsigned* __restrict__ hist, float* __restrict__ msePartial)
{
    __shared__ uint4 sB[3][CHUNK_BYTES / 16];   // 72 KB triple buffer
    __shared__ int   sBest[4][32];

    const int tid  = threadIdx.x;
    const int lane = tid & 63;
    const int wid  = tid >> 6;
    const int col  = lane & 15;   // A-row within tile / D-col (code)
    const int g    = lane >> 4;   // k-group (8 dims) / D row-group
    const int blockPix = blockIdx.x * 128;
    char* sBase = reinterpret_cast<char*>(sB);
    const int sw = (col & 7) << 4;

    size_t zb[2];
#pragma unroll
    for (int m = 0; m < 2; ++m) {
        int pf = blockPix + wid * 32 + m * 16 + col;
        zb[m] = (size_t)(pf >> 14) * 1048576 + (size_t)(pf & 16383);
    }

    float r[2][2][8];   // [m][kh][e], dim = kh*32 + g*8 + e
#pragma unroll
    for (int m = 0; m < 2; ++m)
#pragma unroll
        for (int kh = 0; kh < 2; ++kh)
#pragma unroll
            for (int e = 0; e < 8; ++e)
                r[m][kh][e] = z[zb[m] + (size_t)(kh * 32 + g * 8 + e) * HW];

    for (int i = 0; i < NCB; ++i) {
        const char* gBi = reinterpret_cast<const char*>(gB) + (size_t)i * NCHUNK * CHUNK_BYTES;
        const float* nrm_i = nrmh + i * NE;

        // bf16x3 split of r -> A-frags (once per codebook)
        short8 A[3][2][2];
#pragma unroll
        for (int m = 0; m < 2; ++m)
#pragma unroll
            for (int kh = 0; kh < 2; ++kh)
#pragma unroll
                for (int e = 0; e < 8; ++e) {
                    float t = r[m][kh][e];
                    unsigned short u1 = f2bf(t); t -= bf2f(u1);
                    unsigned short u2 = f2bf(t); t -= bf2f(u2);
                    unsigned short u3 = f2bf(t);
                    A[0][m][kh][e] = (short)u1;
                    A[1][m][kh][e] = (short)u2;
                    A[2][m][kh][e] = (short)u3;
                }

        // prologue: issue chunk 0 into buffer 0 (stays in flight)
#pragma unroll
        for (int k = 0; k < 6; ++k)
            gload16(gBi + k * 4096 + tid * 16, sBase + k * 4096 + tid * 16);

        float maxv[2][4]; int maxi[2][4];
#pragma unroll
        for (int m = 0; m < 2; ++m)
#pragma unroll
            for (int rr = 0; rr < 4; ++rr) { maxv[m][rr] = -3.4e38f; maxi[m][rr] = 0; }

        for (int c = 0; c < NCHUNK; ++c) {
            if (c < NCHUNK - 1) {   // issue next chunk into buf[(c+1)%3]
                const char* gc = gBi + (size_t)(c + 1) * CHUNK_BYTES;
                char* sbn = sBase + ((c + 1) % 3) * CHUNK_BYTES;
#pragma unroll
                for (int k = 0; k < 6; ++k)
                    gload16(gc + k * 4096 + tid * 16, sbn + k * 4096 + tid * 16);
                asm volatile("s_waitcnt vmcnt(6)" ::: "memory");  // own gloads(c) done
            } else {
                asm volatile("s_waitcnt vmcnt(0)" ::: "memory");  // drain last chunk
            }
            __builtin_amdgcn_s_barrier();   // all waves' gloads(c) landed
            const char* sbc = sBase + (c % 3) * CHUNK_BYTES;

#pragma unroll
            for (int sub = 0; sub < 4; ++sub) {
                const int code = (sub << 4) + col;
                float nh = nrm_i[(c << 6) + code];
                f32x4 acc[2];
#pragma unroll
                for (int rr = 0; rr < 4; ++rr) { acc[0][rr] = nh; acc[1][rr] = nh; }

                __builtin_amdgcn_s_setprio(1);
#pragma unroll
                for (int sb = 0; sb < 3; ++sb) {   // B-split-major: 2 B regs live
                    short8 B0 = *reinterpret_cast<const short8*>(
                        sbc + sb * 8192 + ((((code << 7) + (g << 4))) ^ sw));
                    short8 B1 = *reinterpret_cast<const short8*>(
                        sbc + sb * 8192 + ((((code << 7) + 64 + (g << 4))) ^ sw));
#pragma unroll
                    for (int sa = 0; sa < 3 - sb; ++sa) {   // products with sa+sb<=2
                        acc[0] = __builtin_amdgcn_mfma_f32_16x16x32_bf16(A[sa][0][0], B0, acc[0], 0, 0, 0);
                        acc[1] = __builtin_amdgcn_mfma_f32_16x16x32_bf16(A[sa][1][0], B0, acc[1], 0, 0, 0);
                        acc[0] = __builtin_amdgcn_mfma_f32_16x16x32_bf16(A[sa][0][1], B1, acc[0], 0, 0, 0);
                        acc[1] = __builtin_amdgcn_mfma_f32_16x16x32_bf16(A[sa][1][1], B1, acc[1], 0, 0, 0);
                    }
                }
                __builtin_amdgcn_s_setprio(0);

#pragma unroll
                for (int m = 0; m < 2; ++m)
#pragma unroll
                    for (int rr = 0; rr < 4; ++rr) {
                        float s = acc[m][rr];      // argmax s == argmin dist
                        if (s > maxv[m][rr]) { maxv[m][rr] = s; maxi[m][rr] = (c << 6) + code; }
                    }
            }
        }

        // cross-lane argmax within each 16-lane group, idx tie-break
#pragma unroll
        for (int m = 0; m < 2; ++m)
#pragma unroll
            for (int rr = 0; rr < 4; ++rr) {
                float v = maxv[m][rr]; int ix = maxi[m][rr];
#pragma unroll
                for (int off = 1; off < 16; off <<= 1) {
                    float ov = __shfl_xor(v, off, 64);
                    int   oi = __shfl_xor(ix, off, 64);
                    if (ov > v || (ov == v && oi < ix)) { v = ov; ix = oi; }
                }
                maxi[m][rr] = ix;
            }
        // wave-private exchange (same-wave LDS ordering; no barrier needed)
        if (col == 0) {
#pragma unroll
            for (int m = 0; m < 2; ++m)
#pragma unroll
                for (int rr = 0; rr < 4; ++rr)
                    sBest[wid][m * 16 + g * 4 + rr] = maxi[m][rr];
        }

        const float* cbi = cb + (size_t)i * NE * DIM;
        if (lane < 16) {  // idx output + histogram, one writer per row
#pragma unroll
            for (int m = 0; m < 2; ++m) {
                int pfr = blockPix + wid * 32 + m * 16 + lane;
                int bb = pfr >> 14, yy = (pfr >> 7) & 127, xx = pfr & 127;
                int bi = sBest[wid][m * 16 + lane];
                size_t off = (size_t)bb * 65536 + (size_t)(yy >> 2) * 2048
                           + (size_t)(xx >> 2) * 64
                           + (size_t)(((yy & 3) << 2) + (xx & 3)) * 4 + (size_t)i;
                out_idx[off] = (float)bi;
                atomicAdd(&hist[i * NE + bi], 1u);
            }
        }

        // residual update from ORIGINAL fp32 codebook (keeps r exact)
#pragma unroll
        for (int m = 0; m < 2; ++m) {
            const int best = sBest[wid][m * 16 + col];
            const float* er = cbi + (size_t)best * DIM;
#pragma unroll
            for (int kh = 0; kh < 2; ++kh) {
                const float4* e4 = reinterpret_cast<const float4*>(er + kh * 32 + g * 8);
                float4 q0 = e4[0], q1 = e4[1];
                r[m][kh][0] -= q0.x; r[m][kh][1] -= q0.y;
                r[m][kh][2] -= q0.z; r[m][kh][3] -= q0.w;
                r[m][kh][4] -= q1.x; r[m][kh][5] -= q1.y;
                r[m][kh][6] -= q1.z; r[m][kh][7] -= q1.w;
            }
        }

        // MSE partial: (z_q - r_old)^2 = r_new^2
        float s = 0.f;
#pragma unroll
        for (int m = 0; m < 2; ++m)
#pragma unroll
            for (int kh = 0; kh < 2; ++kh)
#pragma unroll
                for (int e = 0; e < 8; ++e) s = fmaf(r[m][kh][e], r[m][kh][e], s);
#pragma unroll
        for (int d_ = 32; d_ > 0; d_ >>= 1) s += __shfl_down(s, d_, 64);
        if (lane == 0) msePartial[i * NWAVES + blockIdx.x * 4 + wid] = s;

        __syncthreads();   // cross-codebook buffer-reuse guard (full drain, 4x total)
    }

    // epilogue: z_q = z - r_final (telescoped straight-through sum)
#pragma unroll
    for (int m = 0; m < 2; ++m)
#pragma unroll
        for (int kh = 0; kh < 2; ++kh)
#pragma unroll
            for (int e = 0; e < 8; ++e) {
                size_t o = zb[m] + (size_t)(kh * 32 + g * 8 + e) * HW;
                out_zq[o] = z[o] - r[m][kh][e];
            }
}

// ---------------- kernel 2: deterministic loss finalize ----------------
__global__ __launch_bounds__(1024) void rvq_finalize(
    const unsigned* __restrict__ hist, const float* __restrict__ msePartial,
    float* __restrict__ out_loss)
{
    __shared__ float red[1024];
    int t = threadIdx.x;
    float loss = 0.f;
    for (int i = 0; i < NCB; ++i) {
        float cnt = (float)hist[i * NE + t];
        float prob = (cnt + EPSF) / (131072.0f + EPSF * 1024.0f);
        red[t] = -prob * logf(prob + EPSF);
        __syncthreads();
        for (int s = 512; s > 0; s >>= 1) { if (t < s) red[t] += red[t + s]; __syncthreads(); }
        float entropy = red[0];
        __syncthreads();
        float acc = 0.f;
#pragma unroll
        for (int k = 0; k < 4; ++k) acc += msePartial[i * NWAVES + k * 1024 + t];
        red[t] = acc;
        __syncthreads();
        for (int s = 512; s > 0; s >>= 1) { if (t < s) red[t] += red[t + s]; __syncthreads(); }
        float mse_sum = red[0];
        __syncthreads();
        loss += 0.25f * (mse_sum / MSE_DENOM) + 0.01f * (logf(1024.0f) - entropy);
    }
    if (t == 0) out_loss[0] = loss;
}

extern "C" void kernel_launch(void* const* d_in, const int* in_sizes, int n_in,
                              void* d_out, int out_size, void* d_ws, size_t ws_size,
                              hipStream_t stream) {
    const float* z  = (const float*)d_in[0];
    const float* cb = (const float*)d_in[1];

    float* out      = (float*)d_out;
    float* out_zq   = out;                    // 8388608
    float* out_loss = out + 8388608;          // 1
    float* out_idx  = out + 8388609;          // 524288 (indices as float)

    unsigned* hist        = (unsigned*)d_ws;                         // 16 KB
    float*    nrmh        = (float*)((char*)d_ws + 16384);           // 16 KB
    float*    msePartial  = (float*)((char*)d_ws + 32768);           // 64 KB (4*4096 f32)
    unsigned short* gB    = (unsigned short*)((char*)d_ws + 163840); // 1.5 MB pre-split image

    hipMemsetAsync(d_ws, 0, 16384, stream);   // zero histogram (deterministic)
    rvq_norms<<<64, 64, 0, stream>>>(cb, nrmh);
    rvq_presplit<<<64, 256, 0, stream>>>(cb, gB);
    rvq_main<<<1024, 256, 0, stream>>>(z, gB, nrmh, cb, out_zq, out_idx, hist, msePartial);
    rvq_finalize<<<1, 1024, 0, stream>>>(hist, msePartial, out_loss);
}

// Round 14
// 382.361 us; speedup vs baseline: 2.0785x; 1.0059x over previous
//
#include <hip/hip_runtime.h>
#include <math.h>

typedef __attribute__((ext_vector_type(8))) short short8;
typedef __attribute__((ext_vector_type(4))) float f32x4;

#define NCB 4
#define NE 1024
#define DIM 64
#define HW 16384
#define NPIX 131072
#define NWAVES 4096            // 1024 blocks * 4 waves
#define MSE_DENOM 8388608.0f   // NPIX*DIM
#define EPSF 1e-5f
#define CHUNK_BYTES 24576      // 3 splits * 64 codes * 64 dims * 2B
#define CHUNK_SHORTS 12288
#define NCHUNK 16              // chunks per codebook

__device__ __forceinline__ unsigned short f2bf(float x) {  // RNE fp32->bf16
    unsigned u = __float_as_uint(x);
    u += 0x7fffu + ((u >> 16) & 1u);
    return (unsigned short)(u >> 16);
}
__device__ __forceinline__ float bf2f(unsigned short h) {  // exact bf16->fp32
    return __uint_as_float(((unsigned)h) << 16);
}

// ------------- kernel 0: -0.5*||e||^2 per code (fp32, exact) -------------
__global__ __launch_bounds__(64) void rvq_norms(const float* __restrict__ cb,
                                                float* __restrict__ nrmh) {
    int code = blockIdx.x * 64 + threadIdx.x;  // 0..4095
    const float4* row = reinterpret_cast<const float4*>(cb + (size_t)code * DIM);
    float s0 = 0.f, s1 = 0.f, s2 = 0.f, s3 = 0.f;
#pragma unroll
    for (int k = 0; k < 16; ++k) {
        float4 v = row[k];
        s0 = fmaf(v.x, v.x, s0); s1 = fmaf(v.y, v.y, s1);
        s2 = fmaf(v.z, v.z, s2); s3 = fmaf(v.w, v.w, s3);
    }
    nrmh[code] = -0.5f * ((s0 + s1) + (s2 + s3));
}

// ------------- kernel 0b: pre-split codebook -> swizzled bf16x3 image ----
// R5-validated layout: [cb i][chunk c(64 codes)] 24KB blobs, 3 planes of
// 8192B, addr=(code*128+dg*32+h*16)^((code&7)<<4). Byte-identical to the
// main kernel's LDS chunk buffer.
__global__ __launch_bounds__(256) void rvq_presplit(const float* __restrict__ cb,
                                                    unsigned short* __restrict__ gB) {
    int blk = blockIdx.x;            // i*16 + c
    int tid = threadIdx.x;
    int code = tid >> 2, dg = tid & 3;
    int c0 = (blk & 15) << 6;
    int i  = blk >> 4;
    const float4* s4 = reinterpret_cast<const float4*>(
        cb + ((size_t)i * NE + c0 + code) * DIM + dg * 16);
    float v[16];
    {
        float4 q;
        q = s4[0]; v[0]=q.x; v[1]=q.y; v[2]=q.z; v[3]=q.w;
        q = s4[1]; v[4]=q.x; v[5]=q.y; v[6]=q.z; v[7]=q.w;
        q = s4[2]; v[8]=q.x; v[9]=q.y; v[10]=q.z; v[11]=q.w;
        q = s4[3]; v[12]=q.x; v[13]=q.y; v[14]=q.z; v[15]=q.w;
    }
    char* outc = reinterpret_cast<char*>(gB + (size_t)blk * CHUNK_SHORTS);
    int linbase = code * 128 + dg * 32;
    int sw = (code & 7) << 4;
#pragma unroll
    for (int h = 0; h < 2; ++h) {
        short8 p1, p2, p3;
#pragma unroll
        for (int e = 0; e < 8; ++e) {
            float t = v[h * 8 + e];
            unsigned short u1 = f2bf(t); t -= bf2f(u1);
            unsigned short u2 = f2bf(t); t -= bf2f(u2);
            unsigned short u3 = f2bf(t);
            p1[e] = (short)u1; p2[e] = (short)u2; p3[e] = (short)u3;
        }
        int a = (linbase + h * 16) ^ sw;
        *reinterpret_cast<short8*>(outc + a)         = p1;
        *reinterpret_cast<short8*>(outc + 8192 + a)  = p2;
        *reinterpret_cast<short8*>(outc + 16384 + a) = p3;
    }
}

// async 16B/lane global->LDS: wave-uniform LDS base, per-lane global src.
__device__ __forceinline__ void gload16(const void* gsrc, void* ldst) {
    __builtin_amdgcn_global_load_lds(
        (const __attribute__((address_space(1))) unsigned int*)gsrc,
        (__attribute__((address_space(3))) unsigned int*)ldst, 16, 0, 0);
}

// ------------- kernel 1: MFMA RVQ, M=32, double-buffer 3-blocks/CU -------
// 1024 blocks x 4 waves, (256,2). R13 (triple-buf 74KB) was clean (VGPR
// 120, no spill) but LDS-capped at 2 blocks/CU -> 2 waves/SIMD: barriers
// + own-wave VALU exposed (MfmaUtil 45). This version: DOUBLE buffer
// (48.5KB -> 3 blocks/CU, 3 waves/SIMD from DIFFERENT blocks) with the
// T3-minimum safe ordering:
//   iter c: __syncthreads()  [own vmcnt drained -> all waves' gloads(c)
//           landed; all waves finished compute(c-1), last reader of the
//           write target]; issue gloads(c+1)->buf[(c+1)&1]; compute(c).
// Chunk-0 issues are hoisted before the PREVIOUS epilogue (cb0: before
// the z-load) so argmax/residual/re-split covers their latency.
// Compute body + numerics byte-identical to the R13-validated lineage.
__global__ __launch_bounds__(256, 2) void rvq_main(
    const float* __restrict__ z, const unsigned short* __restrict__ gB,
    const float* __restrict__ nrmh, const float* __restrict__ cb,
    float* __restrict__ out_zq, float* __restrict__ out_idx,
    unsigned* __restrict__ hist, float* __restrict__ msePartial)
{
    __shared__ uint4 sB[2][CHUNK_BYTES / 16];   // 48 KB double buffer
    __shared__ int   sBest[4][32];

    const int tid  = threadIdx.x;
    const int lane = tid & 63;
    const int wid  = tid >> 6;
    const int col  = lane & 15;   // A-row within tile / D-col (code)
    const int g    = lane >> 4;   // k-group (8 dims) / D row-group
    const int blockPix = blockIdx.x * 128;
    char* sBase = reinterpret_cast<char*>(sB);
    const int sw = (col & 7) << 4;

    // cb0 chunk0: issue before anything else (z-load+split covers latency)
#pragma unroll
    for (int k = 0; k < 6; ++k)
        gload16(reinterpret_cast<const char*>(gB) + k * 4096 + tid * 16,
                sBase + k * 4096 + tid * 16);

    size_t zb[2];
#pragma unroll
    for (int m = 0; m < 2; ++m) {
        int pf = blockPix + wid * 32 + m * 16 + col;
        zb[m] = (size_t)(pf >> 14) * 1048576 + (size_t)(pf & 16383);
    }

    float r[2][2][8];   // [m][kh][e], dim = kh*32 + g*8 + e
#pragma unroll
    for (int m = 0; m < 2; ++m)
#pragma unroll
        for (int kh = 0; kh < 2; ++kh)
#pragma unroll
            for (int e = 0; e < 8; ++e)
                r[m][kh][e] = z[zb[m] + (size_t)(kh * 32 + g * 8 + e) * HW];

    for (int i = 0; i < NCB; ++i) {
        const char* gBi = reinterpret_cast<const char*>(gB) + (size_t)i * NCHUNK * CHUNK_BYTES;
        const float* nrm_i = nrmh + i * NE;

        // bf16x3 split of r -> A-frags (once per codebook)
        short8 A[3][2][2];
#pragma unroll
        for (int m = 0; m < 2; ++m)
#pragma unroll
            for (int kh = 0; kh < 2; ++kh)
#pragma unroll
                for (int e = 0; e < 8; ++e) {
                    float t = r[m][kh][e];
                    unsigned short u1 = f2bf(t); t -= bf2f(u1);
                    unsigned short u2 = f2bf(t); t -= bf2f(u2);
                    unsigned short u3 = f2bf(t);
                    A[0][m][kh][e] = (short)u1;
                    A[1][m][kh][e] = (short)u2;
                    A[2][m][kh][e] = (short)u3;
                }

        float maxv[2][4]; int maxi[2][4];
#pragma unroll
        for (int m = 0; m < 2; ++m)
#pragma unroll
            for (int rr = 0; rr < 4; ++rr) { maxv[m][rr] = -3.4e38f; maxi[m][rr] = 0; }

        for (int c = 0; c < NCHUNK; ++c) {
            // drains own vmcnt (gloads(c) covered by compute(c-1)) + syncs:
            // after this, buf[c&1] is fully populated for ALL waves, and
            // buf[(c+1)&1]'s last readers (compute(c-1)) are all done.
            __syncthreads();
            if (c < NCHUNK - 1) {   // issue next chunk into the freed buffer
                const char* gc = gBi + (size_t)(c + 1) * CHUNK_BYTES;
                char* sbn = sBase + ((c + 1) & 1) * CHUNK_BYTES;
#pragma unroll
                for (int k = 0; k < 6; ++k)
                    gload16(gc + k * 4096 + tid * 16, sbn + k * 4096 + tid * 16);
            }
            const char* sbc = sBase + (c & 1) * CHUNK_BYTES;

#pragma unroll
            for (int sub = 0; sub < 4; ++sub) {
                const int code = (sub << 4) + col;
                float nh = nrm_i[(c << 6) + code];
                f32x4 acc[2];
#pragma unroll
                for (int rr = 0; rr < 4; ++rr) { acc[0][rr] = nh; acc[1][rr] = nh; }

                __builtin_amdgcn_s_setprio(1);
#pragma unroll
                for (int sb = 0; sb < 3; ++sb) {   // B-split-major: 2 B regs live
                    short8 B0 = *reinterpret_cast<const short8*>(
                        sbc + sb * 8192 + ((((code << 7) + (g << 4))) ^ sw));
                    short8 B1 = *reinterpret_cast<const short8*>(
                        sbc + sb * 8192 + ((((code << 7) + 64 + (g << 4))) ^ sw));
#pragma unroll
                    for (int sa = 0; sa < 3 - sb; ++sa) {   // products with sa+sb<=2
                        acc[0] = __builtin_amdgcn_mfma_f32_16x16x32_bf16(A[sa][0][0], B0, acc[0], 0, 0, 0);
                        acc[1] = __builtin_amdgcn_mfma_f32_16x16x32_bf16(A[sa][1][0], B0, acc[1], 0, 0, 0);
                        acc[0] = __builtin_amdgcn_mfma_f32_16x16x32_bf16(A[sa][0][1], B1, acc[0], 0, 0, 0);
                        acc[1] = __builtin_amdgcn_mfma_f32_16x16x32_bf16(A[sa][1][1], B1, acc[1], 0, 0, 0);
                    }
                }
                __builtin_amdgcn_s_setprio(0);

#pragma unroll
                for (int m = 0; m < 2; ++m)
#pragma unroll
                    for (int rr = 0; rr < 4; ++rr) {
                        float s = acc[m][rr];      // argmax s == argmin dist
                        if (s > maxv[m][rr]) { maxv[m][rr] = s; maxi[m][rr] = (c << 6) + code; }
                    }
            }
        }

        // next codebook's chunk0: issue NOW so the epilogue covers latency.
        // buf0's last readers were compute(14) — all waves passed the c=15
        // barrier, so they're done.
        if (i < NCB - 1) {
            const char* gn = reinterpret_cast<const char*>(gB)
                           + (size_t)(i + 1) * NCHUNK * CHUNK_BYTES;
#pragma unroll
            for (int k = 0; k < 6; ++k)
                gload16(gn + k * 4096 + tid * 16, sBase + k * 4096 + tid * 16);
        }

        // cross-lane argmax within each 16-lane group, idx tie-break
#pragma unroll
        for (int m = 0; m < 2; ++m)
#pragma unroll
            for (int rr = 0; rr < 4; ++rr) {
                float v = maxv[m][rr]; int ix = maxi[m][rr];
#pragma unroll
                for (int off = 1; off < 16; off <<= 1) {
                    float ov = __shfl_xor(v, off, 64);
                    int   oi = __shfl_xor(ix, off, 64);
                    if (ov > v || (ov == v && oi < ix)) { v = ov; ix = oi; }
                }
                maxi[m][rr] = ix;
            }
        // wave-private exchange (same-wave LDS ordering; no barrier needed)
        if (col == 0) {
#pragma unroll
            for (int m = 0; m < 2; ++m)
#pragma unroll
                for (int rr = 0; rr < 4; ++rr)
                    sBest[wid][m * 16 + g * 4 + rr] = maxi[m][rr];
        }

        const float* cbi = cb + (size_t)i * NE * DIM;
        if (lane < 16) {  // idx output + histogram, one writer per row
#pragma unroll
            for (int m = 0; m < 2; ++m) {
                int pfr = blockPix + wid * 32 + m * 16 + lane;
                int bb = pfr >> 14, yy = (pfr >> 7) & 127, xx = pfr & 127;
                int bi = sBest[wid][m * 16 + lane];
                size_t off = (size_t)bb * 65536 + (size_t)(yy >> 2) * 2048
                           + (size_t)(xx >> 2) * 64
                           + (size_t)(((yy & 3) << 2) + (xx & 3)) * 4 + (size_t)i;
                out_idx[off] = (float)bi;
                atomicAdd(&hist[i * NE + bi], 1u);
            }
        }

        // residual update from ORIGINAL fp32 codebook (keeps r exact)
#pragma unroll
        for (int m = 0; m < 2; ++m) {
            const int best = sBest[wid][m * 16 + col];
            const float* er = cbi + (size_t)best * DIM;
#pragma unroll
            for (int kh = 0; kh < 2; ++kh) {
                const float4* e4 = reinterpret_cast<const float4*>(er + kh * 32 + g * 8);
                float4 q0 = e4[0], q1 = e4[1];
                r[m][kh][0] -= q0.x; r[m][kh][1] -= q0.y;
                r[m][kh][2] -= q0.z; r[m][kh][3] -= q0.w;
                r[m][kh][4] -= q1.x; r[m][kh][5] -= q1.y;
                r[m][kh][6] -= q1.z; r[m][kh][7] -= q1.w;
            }
        }

        // MSE partial: (z_q - r_old)^2 = r_new^2
        float s = 0.f;
#pragma unroll
        for (int m = 0; m < 2; ++m)
#pragma unroll
            for (int kh = 0; kh < 2; ++kh)
#pragma unroll
                for (int e = 0; e < 8; ++e) s = fmaf(r[m][kh][e], r[m][kh][e], s);
#pragma unroll
        for (int d_ = 32; d_ > 0; d_ >>= 1) s += __shfl_down(s, d_, 64);
        if (lane == 0) msePartial[i * NWAVES + blockIdx.x * 4 + wid] = s;
    }

    // epilogue: z_q = z - r_final (telescoped straight-through sum)
#pragma unroll
    for (int m = 0; m < 2; ++m)
#pragma unroll
        for (int kh = 0; kh < 2; ++kh)
#pragma unroll
            for (int e = 0; e < 8; ++e) {
                size_t o = zb[m] + (size_t)(kh * 32 + g * 8 + e) * HW;
                out_zq[o] = z[o] - r[m][kh][e];
            }
}

// ---------------- kernel 2: deterministic loss finalize ----------------
__global__ __launch_bounds__(1024) void rvq_finalize(
    const unsigned* __restrict__ hist, const float* __restrict__ msePartial,
    float* __restrict__ out_loss)
{
    __shared__ float red[1024];
    int t = threadIdx.x;
    float loss = 0.f;
    for (int i = 0; i < NCB; ++i) {
        float cnt = (float)hist[i * NE + t];
        float prob = (cnt + EPSF) / (131072.0f + EPSF * 1024.0f);
        red[t] = -prob * logf(prob + EPSF);
        __syncthreads();
        for (int s = 512; s > 0; s >>= 1) { if (t < s) red[t] += red[t + s]; __syncthreads(); }
        float entropy = red[0];
        __syncthreads();
        float acc = 0.f;
#pragma unroll
        for (int k = 0; k < 4; ++k) acc += msePartial[i * NWAVES + k * 1024 + t];
        red[t] = acc;
        __syncthreads();
        for (int s = 512; s > 0; s >>= 1) { if (t < s) red[t] += red[t + s]; __syncthreads(); }
        float mse_sum = red[0];
        __syncthreads();
        loss += 0.25f * (mse_sum / MSE_DENOM) + 0.01f * (logf(1024.0f) - entropy);
    }
    if (t == 0) out_loss[0] = loss;
}

extern "C" void kernel_launch(void* const* d_in, const int* in_sizes, int n_in,
                              void* d_out, int out_size, void* d_ws, size_t ws_size,
                              hipStream_t stream) {
    const float* z  = (const float*)d_in[0];
    const float* cb = (const float*)d_in[1];

    float* out      = (float*)d_out;
    float* out_zq   = out;                    // 8388608
    float* out_loss = out + 8388608;          // 1
    float* out_idx  = out + 8388609;          // 524288 (indices as float)

    unsigned* hist        = (unsigned*)d_ws;                         // 16 KB
    float*    nrmh        = (float*)((char*)d_ws + 16384);           // 16 KB
    float*    msePartial  = (float*)((char*)d_ws + 32768);           // 64 KB (4*4096 f32)
    unsigned short* gB    = (unsigned short*)((char*)d_ws + 163840); // 1.5 MB pre-split image

    hipMemsetAsync(d_ws, 0, 16384, stream);   // zero histogram (deterministic)
    rvq_norms<<<64, 64, 0, stream>>>(cb, nrmh);
    rvq_presplit<<<64, 256, 0, stream>>>(cb, gB);
    rvq_main<<<1024, 256, 0, stream>>>(z, gB, nrmh, cb, out_zq, out_idx, hist, msePartial);
    rvq_finalize<<<1, 1024, 0, stream>>>(hist, msePartial, out_loss);
}